// Round 15
// baseline (121.149 us; speedup 1.0000x reference)
//
#include <hip/hip_runtime.h>
#include <stdint.h>

typedef float    f32x4 __attribute__((ext_vector_type(4)));
typedef _Float16 f16x8 __attribute__((ext_vector_type(8)));
typedef _Float16 f16x4 __attribute__((ext_vector_type(4)));
typedef _Float16 f16x2 __attribute__((ext_vector_type(2)));

#define BSZ  32768
#define MHOP 8
#define DDIM 128
#define HDIM 512
#define BT   8        // batches per tile
#define ROWS 64       // BT*MHOP rows per tile
#define NT   8        // tiles per block
#define NBLK 512      // 2 blocks per CU
#define AQLD 136      // padded a_q row stride (f16); 272 B = 17*16 (b128-aligned)

// Relaxed barrier: LDS-visibility only; vmcnt loads stay in flight.
#define BAR_LDS() do { \
    asm volatile("s_waitcnt lgkmcnt(0)" ::: "memory"); \
    __builtin_amdgcn_s_barrier(); \
} while (0)

// Cross-lane on VALU (DPP) instead of the DS pipe.
#define DPP_ADD(s, ctrl) ((s) + __int_as_float(__builtin_amdgcn_update_dpp(0, __float_as_int(s), (ctrl), 0xF, 0xF, true)))
#define DPP_MAX(s, ctrl) fmaxf((s), __int_as_float(__builtin_amdgcn_update_dpp(0, __float_as_int(s), (ctrl), 0xF, 0xF, true)))
#define SWZ_ADD(s, pat)  ((s) + __int_as_float(__builtin_amdgcn_ds_swizzle(__float_as_int(s), (pat))))

// ---- prep: pack W1 [512][256] f32 into per-wave MFMA fragment order, f16.
//      idx = (((w*4+kf)*4+fc)*64 + lane)*8 + j ;
//      h = w*64+fc*16+(lane&15), k = kf*32+(lane>>4)*8+j ; Pk uses k+128.
//      (verified correct in round 10) ----
__global__ void prep_w1_pack(const float* __restrict__ W1,
                             _Float16* __restrict__ Pq, _Float16* __restrict__ Pk) {
    int id = blockIdx.x * blockDim.x + threadIdx.x;   // 8192 = (w,kf,fc,l)
    int l  = id & 63;
    int fc = (id >> 6) & 3;
    int kf = (id >> 8) & 3;
    int w  = id >> 10;
    int h  = w * 64 + fc * 16 + (l & 15);
    int k  = kf * 32 + (l >> 4) * 8;
    const float* srcq = W1 + (size_t)h * 256 + k;
    float4 q0 = *reinterpret_cast<const float4*>(srcq);
    float4 q1 = *reinterpret_cast<const float4*>(srcq + 4);
    float4 k0 = *reinterpret_cast<const float4*>(srcq + 128);
    float4 k1 = *reinterpret_cast<const float4*>(srcq + 132);
    f16x8 pq, pk;
    pq[0]=(_Float16)q0.x; pq[1]=(_Float16)q0.y; pq[2]=(_Float16)q0.z; pq[3]=(_Float16)q0.w;
    pq[4]=(_Float16)q1.x; pq[5]=(_Float16)q1.y; pq[6]=(_Float16)q1.z; pq[7]=(_Float16)q1.w;
    pk[0]=(_Float16)k0.x; pk[1]=(_Float16)k0.y; pk[2]=(_Float16)k0.z; pk[3]=(_Float16)k0.w;
    pk[4]=(_Float16)k1.x; pk[5]=(_Float16)k1.y; pk[6]=(_Float16)k1.z; pk[7]=(_Float16)k1.w;
    *reinterpret_cast<f16x8*>(Pq + (size_t)id * 8) = pq;
    *reinterpret_cast<f16x8*>(Pk + (size_t)id * 8) = pk;
}

__device__ __forceinline__ f16x8 cvt_f16x8(float4 x0, float4 x1) {
    f16x8 p;
    p[0]=(_Float16)x0.x; p[1]=(_Float16)x0.y; p[2]=(_Float16)x0.z; p[3]=(_Float16)x0.w;
    p[4]=(_Float16)x1.x; p[5]=(_Float16)x1.y; p[6]=(_Float16)x1.z; p[7]=(_Float16)x1.w;
    return p;
}

// ---- fused kernel: W1 streamed from packed L2, small LDS (~49 KB) -> 2 blk/CU,
//      double-buffered a_k/a_q/scores -> 1 barrier/tile, DPP epilogue/softmax ----
__global__ void __launch_bounds__(512, 2) fused_kernel(
    const float* __restrict__ q_vec,
    const float* __restrict__ k_vec,
    const float* __restrict__ v_vec,
    const _Float16* __restrict__ Pq,
    const _Float16* __restrict__ Pk,
    const float* __restrict__ W2,
    float* __restrict__ out)
{
    __shared__ __align__(16) _Float16 a_k[2][ROWS * DDIM];   // 2 x 16 KB, swizzled
    __shared__ __align__(16) _Float16 a_q[2][BT * AQLD];     // 2 x 2.125 KB
    __shared__ __align__(16) _Float16 u_lds[HDIM * BT];      // 8 KB, [h][bb], wave-private cols
    __shared__ __align__(16) float scores[2][8][ROWS];       // 2 x 2 KB
    // total ~49.4 KB -> 2 blocks/CU

    const int t  = threadIdx.x;
    const int w  = t >> 6;     // wave 0..7: hidden cols [64w,64w+64), batch w for V
    const int l  = t & 63;
    const int lg = l >> 4;
    const int ll = l & 15;
    const long tile0 = (long)blockIdx.x * NT;

    float w2r[4];
    #pragma unroll
    for (int fc = 0; fc < 4; ++fc) w2r[fc] = W2[w * 64 + fc * 16 + ll];

    // per-wave packed-W1 fragment streams
    const _Float16* pqw = Pq + (size_t)(w * 16) * 512 + l * 8;
    const _Float16* pkw = Pk + (size_t)(w * 16) * 512 + l * 8;

    float4 kr[4]; float2 qr;

    // ---- prologue: load + stage tile 0 ----
    {
        const long b0p = tile0 * BT;
        const float4* ks = reinterpret_cast<const float4*>(k_vec + b0p * (MHOP * DDIM));
        kr[0] = ks[t * 2];           kr[1] = ks[t * 2 + 1];
        kr[2] = ks[(t + 512) * 2];   kr[3] = ks[(t + 512) * 2 + 1];
        qr = *reinterpret_cast<const float2*>(q_vec + (b0p + w) * DDIM + l * 2);

        #pragma unroll
        for (int cc = 0; cc < 2; ++cc) {
            int cid = t + cc * 512, row = cid >> 4, c = cid & 15;
            *reinterpret_cast<f16x8*>(&a_k[0][row * DDIM + ((c ^ (row & 7)) * 8)]) =
                cvt_f16x8(kr[2 * cc], kr[2 * cc + 1]);
        }
        f16x2 qq; qq[0] = (_Float16)qr.x; qq[1] = (_Float16)qr.y;
        *reinterpret_cast<f16x2*>(&a_q[0][w * AQLD + l * 2]) = qq;
    }
    BAR_LDS();

    for (int it = 0; it < NT; ++it) {
        const int p = it & 1;
        const long b0 = (tile0 + it) * BT;

        // ---- issue next tile's k/q loads (drain at staging below) ----
        if (it + 1 < NT) {
            const long bn = b0 + BT;
            const float4* ks = reinterpret_cast<const float4*>(k_vec + bn * (MHOP * DDIM));
            kr[0] = ks[t * 2];           kr[1] = ks[t * 2 + 1];
            kr[2] = ks[(t + 512) * 2];   kr[3] = ks[(t + 512) * 2 + 1];
            qr = *reinterpret_cast<const float2*>(q_vec + (bn + w) * DDIM + l * 2);
        }

        // ---- q-GEMM: u (8 rows x this wave's 64 cols), B streamed from Pq ----
        {
            f32x4 accu[4] = {};
            #pragma unroll
            for (int kf = 0; kf < 4; ++kf) {
                const int kk = kf * 32 + lg * 8;
                f16x8 aq = *reinterpret_cast<const f16x8*>(&a_q[p][(ll & 7) * AQLD + kk]);
                const _Float16* pq_kf = pqw + (size_t)(kf * 4) * 512;
                #pragma unroll
                for (int fc = 0; fc < 4; ++fc) {
                    f16x8 bq = *reinterpret_cast<const f16x8*>(pq_kf + (size_t)fc * 512);
                    accu[fc] = __builtin_amdgcn_mfma_f32_16x16x32_f16(aq, bq, accu[fc], 0, 0, 0);
                }
            }
            if (lg < 2) {
                #pragma unroll
                for (int fc = 0; fc < 4; ++fc) {
                    f16x4 up;
                    up[0]=(_Float16)accu[fc][0]; up[1]=(_Float16)accu[fc][1];
                    up[2]=(_Float16)accu[fc][2]; up[3]=(_Float16)accu[fc][3];
                    *reinterpret_cast<f16x4*>(&u_lds[(w * 64 + fc * 16 + ll) * BT + lg * 4]) = up;
                }
            }
        }

        // ---- k-GEMM: 64 rows x 64 cols/wave, K=128, B streamed from Pk ----
        f32x4 acc[4][4] = {};
        #pragma unroll
        for (int kf = 0; kf < 4; ++kf) {
            const int ch = kf * 4 + lg;
            const _Float16* pk_kf = pkw + (size_t)(kf * 4) * 512;
            f16x8 bf[4];
            #pragma unroll
            for (int fc = 0; fc < 4; ++fc)
                bf[fc] = *reinterpret_cast<const f16x8*>(pk_kf + (size_t)fc * 512);
            #pragma unroll
            for (int fr = 0; fr < 4; ++fr) {
                int row = fr * 16 + ll;
                f16x8 af = *reinterpret_cast<const f16x8*>(
                    &a_k[p][row * DDIM + ((ch ^ (row & 7)) * 8)]);
                #pragma unroll
                for (int fc = 0; fc < 4; ++fc)
                    acc[fr][fc] = __builtin_amdgcn_mfma_f32_16x16x32_f16(af, bf[fc], acc[fr][fc], 0, 0, 0);
            }
        }

        // ---- u reads: 4 x ds_read_b128 + cndmask extract ----
        float uf[4][4];
        #pragma unroll
        for (int fc = 0; fc < 4; ++fc) {
            f16x8 urow = *reinterpret_cast<const f16x8*>(
                &u_lds[(w * 64 + fc * 16 + ll) * BT]);
            #pragma unroll
            for (int fr = 0; fr < 4; ++fr) {
                float lo = (float)urow[fr * 2];
                float hi = (float)urow[fr * 2 + 1];
                uf[fr][fc] = (lg & 2) ? hi : lo;   // bb = fr*2 + (lg>>1)
            }
        }

        // ---- epilogue: s(row) = sum_h W2[h]*relu(t+u); 16-lane DPP reduce ----
        #pragma unroll
        for (int fr = 0; fr < 4; ++fr) {
            float sj[4];
            #pragma unroll
            for (int j = 0; j < 4; ++j) {
                float s = 0.f;
                #pragma unroll
                for (int fc = 0; fc < 4; ++fc)
                    s += w2r[fc] * fmaxf(acc[fr][fc][j] + uf[fr][fc], 0.f);
                s = DPP_ADD(s, 0xB1);    // xor1
                s = DPP_ADD(s, 0x4E);    // xor2
                s = DPP_ADD(s, 0x141);   // xor4 (row_half_mirror)
                s = DPP_ADD(s, 0x140);   // xor8 (row_mirror)
                sj[j] = s;
            }
            if (ll == 0) {
                f32x4 sv; sv[0]=sj[0]; sv[1]=sj[1]; sv[2]=sj[2]; sv[3]=sj[3];
                *reinterpret_cast<f32x4*>(&scores[p][w][fr * 16 + lg * 4]) = sv;
            }
        }

        // ---- stage next tile into buf p^1 (vmcnt drains here at first use) ----
        if (it + 1 < NT) {
            #pragma unroll
            for (int cc = 0; cc < 2; ++cc) {
                int cid = t + cc * 512, row = cid >> 4, c = cid & 15;
                *reinterpret_cast<f16x8*>(&a_k[p ^ 1][row * DDIM + ((c ^ (row & 7)) * 8)]) =
                    cvt_f16x8(kr[2 * cc], kr[2 * cc + 1]);
            }
            f16x2 qq; qq[0] = (_Float16)qr.x; qq[1] = (_Float16)qr.y;
            *reinterpret_cast<f16x2*>(&a_q[p ^ 1][w * AQLD + l * 2]) = qq;
        }
        BAR_LDS();   // single barrier/tile: scores[p] + staged bufs visible

        // ---- this tile's v loads (issued before softmax VALU) ----
        float2 vr[8];
        {
            const float* vb = v_vec + (b0 + w) * (MHOP * DDIM) + l * 2;
            #pragma unroll
            for (int m = 0; m < MHOP; ++m)
                vr[m] = *reinterpret_cast<const float2*>(vb + m * DDIM);
        }

        // ---- wave-redundant softmax for batch w ----
        float attn;
        {
            const int m = l & 7, g = l >> 3;
            float s = scores[p][g][w * 8 + m];
            s = SWZ_ADD(s, 0x201F);          // xor8
            s = SWZ_ADD(s, 0x401F);          // xor16
            s += __shfl_xor(s, 32);          // xor32
            float mx = s;
            mx = DPP_MAX(mx, 0xB1);
            mx = DPP_MAX(mx, 0x4E);
            mx = DPP_MAX(mx, 0x141);
            float e = __expf(s - mx);
            float sum = e;
            sum = DPP_ADD(sum, 0xB1);
            sum = DPP_ADD(sum, 0x4E);
            sum = DPP_ADD(sum, 0x141);
            attn = e / sum;                  // lane l holds attn(l&7) for batch w
        }

        // ---- output: out[w][2l..2l+1] = sum_m attn(m)*v[m] ----
        {
            float a0 = 0.f, a1 = 0.f;
            #pragma unroll
            for (int m = 0; m < MHOP; ++m) {
                float at = __shfl(attn, m, 8);
                a0 += at * vr[m].x;
                a1 += at * vr[m].y;
            }
            float2 o; o.x = a0; o.y = a1;
            *reinterpret_cast<float2*>(out + (b0 + w) * DDIM + l * 2) = o;
        }
    }
}

extern "C" void kernel_launch(void* const* d_in, const int* in_sizes, int n_in,
                              void* d_out, int out_size, void* d_ws, size_t ws_size,
                              hipStream_t stream) {
    const float* q  = (const float*)d_in[0];
    const float* k  = (const float*)d_in[1];
    const float* v  = (const float*)d_in[2];
    const float* W1 = (const float*)d_in[3];
    const float* W2 = (const float*)d_in[4];

    _Float16* Pq = (_Float16*)d_ws;                       // 128 KB
    _Float16* Pk = (_Float16*)((char*)d_ws + 128 * 1024); // 128 KB

    prep_w1_pack<<<32, 256, 0, stream>>>(W1, Pq, Pk);
    fused_kernel<<<NBLK, 512, 0, stream>>>(q, k, v, Pq, Pk, W2, (float*)d_out);
}